// Round 8
// baseline (342.621 us; speedup 1.0000x reference)
//
#include <hip/hip_runtime.h>

#define DEV __device__ __forceinline__

using bf16x8 = __attribute__((ext_vector_type(8))) __bf16;
using f32x4  = __attribute__((ext_vector_type(4))) float;
typedef unsigned int u32;
typedef unsigned short u16;
typedef unsigned long long u64;

static constexpr int Bb = 4, Ss = 1024, Ee = 1024, Hh = 16, Dd = 64, Ff = 4096;
static constexpr int Mm = Bb * Ss; // 4096 rows

// ---------- helpers ----------
DEV u16 f2bf(float f) {                 // fp32 -> bf16 RNE (finite inputs)
  union { float f; u32 u; } v; v.f = f;
  u32 r = v.u + 0x7fffu + ((v.u >> 16) & 1u);
  return (u16)(r >> 16);
}

DEV void gload16(const void* g, void* lds) {   // async global->LDS, 16B/lane
  __builtin_amdgcn_global_load_lds(
      (const __attribute__((address_space(1))) void*)(u64)g,
      (__attribute__((address_space(3))) void*)(u32)(u64)lds,
      16, 0, 0);
}

DEV float gelu_tanh(float x) {          // gelu_new (tanh approx)
  float x3 = x * x * x;
  float t  = tanhf(0.7978845608028654f * (x + 0.044715f * x3));
  return 0.5f * x * (1.0f + t);
}

// XOR-swizzle for [R][64] bf16 LDS tiles (attention): 16B-slot ^= row&7
DEV int swz(int row, int col) { return row * 64 + (col ^ ((row & 7) << 3)); }

DEV f32x4 MFMA(bf16x8 a, bf16x8 b, f32x4 c) {
  return __builtin_amdgcn_mfma_f32_16x16x32_bf16(a, b, c, 0, 0, 0);
}

// ---------- fp32 -> bf16 convert (8 elems/thread) ----------
__global__ __launch_bounds__(256) void cvt_bf16(const float* __restrict__ in,
                                                u16* __restrict__ out, int n) {
  int i = (blockIdx.x * 256 + threadIdx.x) * 8;
  if (i >= n) return;
  float4 a = *(const float4*)(in + i);
  float4 b = *(const float4*)(in + i + 4);
  uint4 o;
  o.x = (u32)f2bf(a.x) | ((u32)f2bf(a.y) << 16);
  o.y = (u32)f2bf(a.z) | ((u32)f2bf(a.w) << 16);
  o.z = (u32)f2bf(b.x) | ((u32)f2bf(b.y) << 16);
  o.w = (u32)f2bf(b.z) | ((u32)f2bf(b.w) << 16);
  *(uint4*)(out + i) = o;
}

// ---------- LayerNorm: one row (1024) per block, fp32 in -> bf16 out ----------
__global__ __launch_bounds__(256) void ln_kernel(const float* __restrict__ x,
                                                 const float* __restrict__ scale,
                                                 const float* __restrict__ bias,
                                                 u16* __restrict__ h) {
  const int row = blockIdx.x, tid = threadIdx.x;
  const float4 v = ((const float4*)(x + (size_t)row * Ee))[tid];
  float s  = v.x + v.y + v.z + v.w;
  float ss = v.x * v.x + v.y * v.y + v.z * v.z + v.w * v.w;
  for (int m = 1; m < 64; m <<= 1) {
    s  += __shfl_xor(s, m, 64);
    ss += __shfl_xor(ss, m, 64);
  }
  __shared__ float red[8];
  const int w = tid >> 6, ln = tid & 63;
  if (ln == 0) { red[w * 2] = s; red[w * 2 + 1] = ss; }
  __syncthreads();
  s  = red[0] + red[2] + red[4] + red[6];
  ss = red[1] + red[3] + red[5] + red[7];
  const float mu   = s * (1.0f / Ee);
  const float var  = ss * (1.0f / Ee) - mu * mu;
  const float rstd = rsqrtf(var + 1e-5f);
  const float4 sc = ((const float4*)scale)[tid];
  const float4 bi = ((const float4*)bias)[tid];
  ushort4 o;
  o.x = f2bf((v.x - mu) * rstd * sc.x + bi.x);
  o.y = f2bf((v.y - mu) * rstd * sc.y + bi.y);
  o.z = f2bf((v.z - mu) * rstd * sc.z + bi.z);
  o.w = f2bf((v.w - mu) * rstd * sc.w + bi.w);
  ((ushort4*)(h + (size_t)row * Ee))[tid] = o;
}

// ================= TLP-first GEMM: C = A @ B^T (+epilogue) ==================
// Tile BM x BN = (AM*32) x (AN*32); 4 waves in 2x2, each (AM*16)x(AN*16).
// BK=32. 2-deep ring, small LDS (<=24KB) -> 6 blocks/CU resident.
// EPI: 0 = QKV split; 1 = +bias +resid -> fp32; 2 = gelu(+bias) -> bf16
template <int EPI, int AM, int AN>
__global__ __launch_bounds__(256, 6) void gemm3(
    const u16* __restrict__ A, const u16* __restrict__ Bw,
    const float* __restrict__ bias, const float* __restrict__ resid,
    float* __restrict__ outf, u16* __restrict__ outb,
    u16* __restrict__ q, u16* __restrict__ k, u16* __restrict__ v,
    int N, int K) {
  constexpr int BM = AM * 32, BN = AN * 32;
  constexpr int GA = BM / 64, GB = BN / 64;     // gload16 per thread per tile
  __shared__ u16 As[2][BM * 32];
  __shared__ u16 Bs[2][BN * 32];
  const int tid = threadIdx.x;
  const int w = tid >> 6, ln = tid & 63;
  const int lr = ln & 15, lg = ln >> 4;
  const int wr = w >> 1, wc = w & 1;

  // XCD bijective block swizzle (all grids here have nwg % 8 == 0)
  const int nwg = gridDim.x * gridDim.y;
  const int bid = blockIdx.y * gridDim.x + blockIdx.x;
  const int sid = (bid & 7) * (nwg >> 3) + (bid >> 3);
  const int bx = sid % gridDim.x, by = sid / gridDim.x;
  const int tm = by * BM, tn = bx * BN;

  f32x4 acc[AM][AN];
  f32x4 zero4 = {0.f, 0.f, 0.f, 0.f};
#pragma unroll
  for (int i = 0; i < AM; ++i)
#pragma unroll
    for (int j = 0; j < AN; ++j) acc[i][j] = zero4;

  const int r0 = tid >> 2;
  const int cs = ((tid & 3) ^ (r0 & 3)) * 8;    // pre-swizzled source slot
  const u16* aP[GA];
  const u16* bP[GB];
#pragma unroll
  for (int i = 0; i < GA; ++i) aP[i] = A + (size_t)(tm + r0 + i * 64) * K + cs;
#pragma unroll
  for (int i = 0; i < GB; ++i) bP[i] = Bw + (size_t)(tn + r0 + i * 64) * K + cs;

  auto STAGE = [&](int buf, int k0) {
#pragma unroll
    for (int i = 0; i < GA; ++i)
      gload16(aP[i] + k0, &As[buf][(tid + i * 256) * 8]);
#pragma unroll
    for (int i = 0; i < GB; ++i)
      gload16(bP[i] + k0, &Bs[buf][(tid + i * 256) * 8]);
  };

  const int fsl = (lg ^ (lr & 3)) << 3;   // swizzled 16B slot on read
  const int nt = K >> 5;
  STAGE(0, 0);
  asm volatile("s_waitcnt vmcnt(0)" ::: "memory");
  __builtin_amdgcn_s_barrier();

  for (int t = 0; t < nt; ++t) {
    if (t + 1 < nt) STAGE((t + 1) & 1, (t + 1) << 5);   // into the other buffer
    const u16* Ab = &As[t & 1][0];
    const u16* Bbuf = &Bs[t & 1][0];
    bf16x8 af[AM], bf[AN];
#pragma unroll
    for (int mi = 0; mi < AM; ++mi)
      af[mi] = *(const bf16x8*)&Ab[(wr * AM * 16 + mi * 16 + lr) * 32 + fsl];
#pragma unroll
    for (int ni = 0; ni < AN; ++ni)
      bf[ni] = *(const bf16x8*)&Bbuf[(wc * AN * 16 + ni * 16 + lr) * 32 + fsl];
#pragma unroll
    for (int mi = 0; mi < AM; ++mi)
#pragma unroll
      for (int ni = 0; ni < AN; ++ni)
        acc[mi][ni] = MFMA(af[mi], bf[ni], acc[mi][ni]);
    asm volatile("s_waitcnt vmcnt(0)" ::: "memory");
    __builtin_amdgcn_s_barrier();
  }

  // ---- epilogue
#pragma unroll
  for (int mi = 0; mi < AM; ++mi) {
#pragma unroll
    for (int ni = 0; ni < AN; ++ni) {
      const int gc = tn + wc * AN * 16 + ni * 16 + lr;
#pragma unroll
      for (int j = 0; j < 4; ++j) {
        const int gr = tm + wr * AM * 16 + mi * 16 + lg * 4 + j;
        float val = acc[mi][ni][j] + bias[gc];
        if constexpr (EPI == 0) {
          const int which = gc >> 10, hh = (gc >> 6) & 15, dd = gc & 63;
          const int bb2 = gr >> 10, ss2 = gr & 1023;
          const size_t dst = ((size_t)(bb2 * 16 + hh) * 1024 + ss2) * 64 + dd;
          if (which == 0)      q[dst] = f2bf(val * 0.125f);   // 1/sqrt(64)
          else if (which == 1) k[dst] = f2bf(val);
          else                 v[dst] = f2bf(val);
        } else if constexpr (EPI == 1) {
          const size_t idx = (size_t)gr * N + gc;
          outf[idx] = val + resid[idx];
        } else {
          outb[(size_t)gr * N + gc] = f2bf(gelu_tanh(val));
        }
      }
    }
  }
}

// ---------- flash attention v2 (no mask). Q pre-scaled. [B,H,S,D] bf16 -----
// 64 q-rows/block, 4 waves x 16 rows; KV tiles of 64.
// Q in regs (loaded once); K B-frags direct from global (L2-resident);
// V double-buffered in LDS with rotated transpose writes (bank-conflict-free);
// P through LDS. 2 syncs/iter.
__global__ __launch_bounds__(256) void attn2(const u16* __restrict__ qg,
                                             const u16* __restrict__ kg,
                                             const u16* __restrict__ vg,
                                             u16* __restrict__ ao) {
  __shared__ u16 Vt[2][64 * 64];   // [dbuf][d][kv] swizzled
  __shared__ u16 Ps[64 * 64];      // [q][kv] swizzled
  const int tid = threadIdx.x;
  const int w = tid >> 6, ln = tid & 63;
  const int lr = ln & 15, lg = ln >> 4;
  const int bh = blockIdx.y;
  const int q0 = blockIdx.x * 64;
  const size_t head = (size_t)bh * (Ss * Dd);

  // Q fragments: row q0 + w*16 + lr, 16B contiguous per lane
  bf16x8 aq[2];
  {
    const u16* qrow = qg + head + (size_t)(q0 + w * 16 + lr) * Dd;
    aq[0] = *(const bf16x8*)(qrow + lg * 8);
    aq[1] = *(const bf16x8*)(qrow + 32 + lg * 8);
  }

  const int kv0 = tid >> 3;          // 0..31 (+32 on second chunk)
  const int dsel = tid & 7, d0 = dsel * 8;

  // V-transpose store with ROTATED write order: per step jj, lane writes
  // dd&7 = (jj+dsel)&7 -> swizzle term varies across lane groups -> no
  // column-pileup (fix for the 14.7M-conflict scatter).
  auto VSTORE = [&](int buf, uint4 dv, int kv) {
    const u16* pv = (const u16*)&dv;
#pragma unroll
    for (int jj = 0; jj < 8; ++jj) {
      const int j = (jj + dsel) & 7;
      const int dd = d0 + j;
      Vt[buf][dd * 64 + (kv & 7) + (((kv >> 3) ^ (dd & 7)) << 3)] = pv[j];
    }
  };

  { // prologue: stage V tile 0
    const u16* vsrc = vg + head;
    uint4 a = *(const uint4*)(vsrc + (size_t)kv0 * Dd + d0);
    uint4 b = *(const uint4*)(vsrc + (size_t)(32 + kv0) * Dd + d0);
    VSTORE(0, a, kv0);
    VSTORE(0, b, 32 + kv0);
  }
  __syncthreads();

  f32x4 zero4 = {0.f, 0.f, 0.f, 0.f};
  f32x4 acc_o[4] = {zero4, zero4, zero4, zero4};
  float mrow[4] = {-1e30f, -1e30f, -1e30f, -1e30f};
  float lrow[4] = {0.f, 0.f, 0.f, 0.f};

  for (int kt = 0; kt < 16; ++kt) {
    const int cur = kt & 1, nc = cur ^ 1;
    const bool more = (kt + 1) < 16;

    // issue V(kt+1) loads early (hidden under QK^T + softmax)
    uint4 dv0, dv1;
    if (more) {
      const u16* vnxt = vg + head + (size_t)(kt + 1) * 64 * Dd;
      dv0 = *(const uint4*)(vnxt + (size_t)kv0 * Dd + d0);
      dv1 = *(const uint4*)(vnxt + (size_t)(32 + kv0) * Dd + d0);
    }

    // QK^T with K read directly from global (L2-resident per head)
    const u16* kbase = kg + head + (size_t)kt * 64 * Dd;
    f32x4 sa[4];
#pragma unroll
    for (int kf = 0; kf < 4; ++kf) {
      const u16* krow = kbase + (size_t)(kf * 16 + lr) * Dd;
      bf16x8 bk0 = *(const bf16x8*)(krow + lg * 8);
      bf16x8 bk1 = *(const bf16x8*)(krow + 32 + lg * 8);
      f32x4 s = zero4;
      s = MFMA(aq[0], bk0, s);
      s = MFMA(aq[1], bk1, s);
      sa[kf] = s;
    }

    // online softmax (row = q, stats over kf frags + 16-lane kv group)
#pragma unroll
    for (int j = 0; j < 4; ++j) {
      float mx = fmaxf(fmaxf(sa[0][j], sa[1][j]), fmaxf(sa[2][j], sa[3][j]));
      mx = fmaxf(mx, __shfl_xor(mx, 1, 64));
      mx = fmaxf(mx, __shfl_xor(mx, 2, 64));
      mx = fmaxf(mx, __shfl_xor(mx, 4, 64));
      mx = fmaxf(mx, __shfl_xor(mx, 8, 64));
      const float nm = fmaxf(mrow[j], mx);
      const float corr = __expf(mrow[j] - nm);
      mrow[j] = nm;
      float ssum = 0.f;
#pragma unroll
      for (int kf = 0; kf < 4; ++kf) {
        const float p = __expf(sa[kf][j] - nm);
        sa[kf][j] = p;
        ssum += p;
      }
      ssum += __shfl_xor(ssum, 1, 64);
      ssum += __shfl_xor(ssum, 2, 64);
      ssum += __shfl_xor(ssum, 4, 64);
      ssum += __shfl_xor(ssum, 8, 64);
      lrow[j] = lrow[j] * corr + ssum;
#pragma unroll
      for (int df = 0; df < 4; ++df) acc_o[df][j] *= corr;
    }

    // P -> LDS (bf16, swizzled)
#pragma unroll
    for (int kf = 0; kf < 4; ++kf)
#pragma unroll
      for (int j = 0; j < 4; ++j)
        Ps[swz(w * 16 + lg * 4 + j, kf * 16 + lr)] = f2bf(sa[kf][j]);

    __syncthreads();   // SYNC1: P visible; Vt[cur] complete (prev SYNC2)

    // PV: O[q 16][d 64] += P @ V  from Vt[cur]
    bf16x8 ap[2];
#pragma unroll
    for (int kk = 0; kk < 2; ++kk)
      ap[kk] = *(const bf16x8*)&Ps[swz(w * 16 + lr, kk * 32 + lg * 8)];
#pragma unroll
    for (int df = 0; df < 4; ++df) {
#pragma unroll
      for (int kk = 0; kk < 2; ++kk) {
        bf16x8 bv = *(const bf16x8*)&Vt[cur][swz(df * 16 + lr, kk * 32 + lg * 8)];
        acc_o[df] = MFMA(ap[kk], bv, acc_o[df]);
      }
    }

    // stage V(kt+1) into the other buffer (readers only after SYNC2)
    if (more) {
      VSTORE(nc, dv0, kv0);
      VSTORE(nc, dv1, 32 + kv0);
    }
    __syncthreads();   // SYNC2: Vt[nc] ready; Ps free for next iter
  }

  // epilogue: O/l -> attn_out [B,S,E] bf16
  const int b = bh >> 4, h = bh & 15;
#pragma unroll
  for (int df = 0; df < 4; ++df) {
#pragma unroll
    for (int j = 0; j < 4; ++j) {
      const int srow = q0 + w * 16 + lg * 4 + j;
      const int e = h * 64 + df * 16 + lr;
      ao[((size_t)b * Ss + srow) * Ee + e] = f2bf(acc_o[df][j] / lrow[j]);
    }
  }
}

// ---------- launcher ----------
extern "C" void kernel_launch(void* const* d_in, const int* in_sizes, int n_in,
                              void* d_out, int out_size, void* d_ws, size_t ws_size,
                              hipStream_t stream) {
  const float* x      = (const float*)d_in[0];
  const float* ln1_s  = (const float*)d_in[1];
  const float* ln1_b  = (const float*)d_in[2];
  const float* w_attn = (const float*)d_in[3];
  const float* b_attn = (const float*)d_in[4];
  const float* w_proj = (const float*)d_in[5];
  const float* b_proj = (const float*)d_in[6];
  const float* ln2_s  = (const float*)d_in[7];
  const float* ln2_b  = (const float*)d_in[8];
  const float* w_fc   = (const float*)d_in[9];
  const float* b_fc   = (const float*)d_in[10];
  const float* w_proj2= (const float*)d_in[11];
  const float* b_proj2= (const float*)d_in[12];
  float* out = (float*)d_out;

  char* base = (char*)d_ws;
  size_t off = 0;
  auto alloc = [&](size_t bytes) { char* p = base + off; off += bytes; return p; };
  u16* wA   = (u16*)alloc((size_t)3 * Ee * Ee * 2);  // 6 MB
  u16* wP   = (u16*)alloc((size_t)Ee * Ee * 2);      // 2 MB
  u16* wF   = (u16*)alloc((size_t)Ff * Ee * 2);      // 8 MB
  u16* wP2  = (u16*)alloc((size_t)Ee * Ff * 2);      // 8 MB
  u16* h1   = (u16*)alloc((size_t)Mm * Ee * 2);      // 8 MB (reused as h2)
  u16* qws  = (u16*)alloc((size_t)Mm * Ee * 2);      // 8 MB (q; mfc alias start)
  u16* kws  = (u16*)alloc((size_t)Mm * Ee * 2);      // 8 MB (k)
  u16* vws  = (u16*)alloc((size_t)Mm * Ee * 2);      // 8 MB (v)
  u16* aws  = (u16*)alloc((size_t)Mm * Ee * 2);      // 8 MB (attn out)
  float* x1 = (float*)alloc((size_t)Mm * Ee * 4);    // 16 MB
  u16* mfc  = qws;  // [4096,4096] bf16 aliases q/k/v/ao (all dead by then)

  // weights -> bf16 (every call; deterministic)
  cvt_bf16<<<3 * Ee * Ee / 2048, 256, 0, stream>>>(w_attn, wA, 3 * Ee * Ee);
  cvt_bf16<<<Ee * Ee / 2048, 256, 0, stream>>>(w_proj, wP, Ee * Ee);
  cvt_bf16<<<Ff * Ee / 2048, 256, 0, stream>>>(w_fc, wF, Ff * Ee);
  cvt_bf16<<<Ee * Ff / 2048, 256, 0, stream>>>(w_proj2, wP2, Ee * Ff);

  // LN1 -> h1
  ln_kernel<<<Mm, 256, 0, stream>>>(x, ln1_s, ln1_b, h1);
  // QKV GEMM: [4096,1024]@[1024,3072]^T -> q,k,v [B,H,S,D]  (128x64 tiles)
  gemm3<0, 4, 2><<<dim3(48, 32), 256, 0, stream>>>(h1, wA, b_attn, nullptr,
                                                   nullptr, nullptr, qws, kws, vws,
                                                   3 * Ee, Ee);
  // attention
  attn2<<<dim3(16, 64), 256, 0, stream>>>(qws, kws, vws, aws);
  // proj + residual -> x1 (fp32)  (64x64 tiles)
  gemm3<1, 2, 2><<<dim3(16, 64), 256, 0, stream>>>(aws, wP, b_proj, x,
                                                   x1, nullptr, nullptr, nullptr, nullptr,
                                                   Ee, Ee);
  // LN2 -> h1 (as h2)
  ln_kernel<<<Mm, 256, 0, stream>>>(x1, ln2_s, ln2_b, h1);
  // fc + gelu -> mfc (bf16)  (128x64 tiles)
  gemm3<2, 4, 2><<<dim3(64, 32), 256, 0, stream>>>(h1, wF, b_fc, nullptr,
                                                   nullptr, mfc, nullptr, nullptr, nullptr,
                                                   Ff, Ee);
  // proj2 + residual -> out (fp32)  (64x64 tiles)
  gemm3<1, 2, 2><<<dim3(16, 64), 256, 0, stream>>>(mfc, wP2, b_proj2, x1,
                                                   out, nullptr, nullptr, nullptr, nullptr,
                                                   Ee, Ff);
}

// Round 9
// 315.336 us; speedup vs baseline: 1.0865x; 1.0865x over previous
//
#include <hip/hip_runtime.h>

#define DEV __device__ __forceinline__

using bf16x8 = __attribute__((ext_vector_type(8))) __bf16;
using f32x4  = __attribute__((ext_vector_type(4))) float;
typedef unsigned int u32;
typedef unsigned short u16;
typedef unsigned long long u64;

static constexpr int Bb = 4, Ss = 1024, Ee = 1024, Hh = 16, Dd = 64, Ff = 4096;
static constexpr int Mm = Bb * Ss; // 4096 rows

// ---------- helpers ----------
DEV u16 f2bf(float f) {                 // fp32 -> bf16 RNE (finite inputs)
  union { float f; u32 u; } v; v.f = f;
  u32 r = v.u + 0x7fffu + ((v.u >> 16) & 1u);
  return (u16)(r >> 16);
}

DEV void gload16(const void* g, void* lds) {   // async global->LDS, 16B/lane
  __builtin_amdgcn_global_load_lds(
      (const __attribute__((address_space(1))) void*)(u64)g,
      (__attribute__((address_space(3))) void*)(u32)(u64)lds,
      16, 0, 0);
}

DEV float gelu_tanh(float x) {          // gelu_new (tanh approx)
  float x3 = x * x * x;
  float t  = tanhf(0.7978845608028654f * (x + 0.044715f * x3));
  return 0.5f * x * (1.0f + t);
}

// XOR-swizzle for [R][64] bf16 LDS tiles (attention): 16B-slot ^= row&7
DEV int swz(int row, int col) { return row * 64 + (col ^ ((row & 7) << 3)); }

DEV f32x4 MFMA(bf16x8 a, bf16x8 b, f32x4 c) {
  return __builtin_amdgcn_mfma_f32_16x16x32_bf16(a, b, c, 0, 0, 0);
}

// ---------- fp32 -> bf16 convert (8 elems/thread) ----------
__global__ __launch_bounds__(256) void cvt_bf16(const float* __restrict__ in,
                                                u16* __restrict__ out, int n) {
  int i = (blockIdx.x * 256 + threadIdx.x) * 8;
  if (i >= n) return;
  float4 a = *(const float4*)(in + i);
  float4 b = *(const float4*)(in + i + 4);
  uint4 o;
  o.x = (u32)f2bf(a.x) | ((u32)f2bf(a.y) << 16);
  o.y = (u32)f2bf(a.z) | ((u32)f2bf(a.w) << 16);
  o.z = (u32)f2bf(b.x) | ((u32)f2bf(b.y) << 16);
  o.w = (u32)f2bf(b.z) | ((u32)f2bf(b.w) << 16);
  *(uint4*)(out + i) = o;
}

// ---------- LayerNorm: one row (1024) per block, fp32 in -> bf16 out ----------
__global__ __launch_bounds__(256) void ln_kernel(const float* __restrict__ x,
                                                 const float* __restrict__ scale,
                                                 const float* __restrict__ bias,
                                                 u16* __restrict__ h) {
  const int row = blockIdx.x, tid = threadIdx.x;
  const float4 v = ((const float4*)(x + (size_t)row * Ee))[tid];
  float s  = v.x + v.y + v.z + v.w;
  float ss = v.x * v.x + v.y * v.y + v.z * v.z + v.w * v.w;
  for (int m = 1; m < 64; m <<= 1) {
    s  += __shfl_xor(s, m, 64);
    ss += __shfl_xor(ss, m, 64);
  }
  __shared__ float red[8];
  const int w = tid >> 6, ln = tid & 63;
  if (ln == 0) { red[w * 2] = s; red[w * 2 + 1] = ss; }
  __syncthreads();
  s  = red[0] + red[2] + red[4] + red[6];
  ss = red[1] + red[3] + red[5] + red[7];
  const float mu   = s * (1.0f / Ee);
  const float var  = ss * (1.0f / Ee) - mu * mu;
  const float rstd = rsqrtf(var + 1e-5f);
  const float4 sc = ((const float4*)scale)[tid];
  const float4 bi = ((const float4*)bias)[tid];
  ushort4 o;
  o.x = f2bf((v.x - mu) * rstd * sc.x + bi.x);
  o.y = f2bf((v.y - mu) * rstd * sc.y + bi.y);
  o.z = f2bf((v.z - mu) * rstd * sc.z + bi.z);
  o.w = f2bf((v.w - mu) * rstd * sc.w + bi.w);
  ((ushort4*)(h + (size_t)row * Ee))[tid] = o;
}

// ================= TLP-first GEMM: C = A @ B^T (+epilogue) ==================
// Tile BM x BN = (AM*32) x (AN*32); 4 waves in 2x2, each (AM*16)x(AN*16).
// BK=32. 2-deep ring, small LDS (<=24KB) -> 6 blocks/CU resident.
// EPI: 0 = QKV split; 1 = +bias +resid -> fp32; 2 = gelu(+bias) -> bf16
template <int EPI, int AM, int AN>
__global__ __launch_bounds__(256, 6) void gemm3(
    const u16* __restrict__ A, const u16* __restrict__ Bw,
    const float* __restrict__ bias, const float* __restrict__ resid,
    float* __restrict__ outf, u16* __restrict__ outb,
    u16* __restrict__ q, u16* __restrict__ k, u16* __restrict__ v,
    int N, int K) {
  constexpr int BM = AM * 32, BN = AN * 32;
  constexpr int GA = BM / 64, GB = BN / 64;     // gload16 per thread per tile
  __shared__ u16 As[2][BM * 32];
  __shared__ u16 Bs[2][BN * 32];
  const int tid = threadIdx.x;
  const int w = tid >> 6, ln = tid & 63;
  const int lr = ln & 15, lg = ln >> 4;
  const int wr = w >> 1, wc = w & 1;

  // XCD bijective block swizzle (all grids here have nwg % 8 == 0)
  const int nwg = gridDim.x * gridDim.y;
  const int bid = blockIdx.y * gridDim.x + blockIdx.x;
  const int sid = (bid & 7) * (nwg >> 3) + (bid >> 3);
  const int bx = sid % gridDim.x, by = sid / gridDim.x;
  const int tm = by * BM, tn = bx * BN;

  f32x4 acc[AM][AN];
  f32x4 zero4 = {0.f, 0.f, 0.f, 0.f};
#pragma unroll
  for (int i = 0; i < AM; ++i)
#pragma unroll
    for (int j = 0; j < AN; ++j) acc[i][j] = zero4;

  const int r0 = tid >> 2;
  const int cs = ((tid & 3) ^ (r0 & 3)) * 8;    // pre-swizzled source slot
  const u16* aP[GA];
  const u16* bP[GB];
#pragma unroll
  for (int i = 0; i < GA; ++i) aP[i] = A + (size_t)(tm + r0 + i * 64) * K + cs;
#pragma unroll
  for (int i = 0; i < GB; ++i) bP[i] = Bw + (size_t)(tn + r0 + i * 64) * K + cs;

  auto STAGE = [&](int buf, int k0) {
#pragma unroll
    for (int i = 0; i < GA; ++i)
      gload16(aP[i] + k0, &As[buf][(tid + i * 256) * 8]);
#pragma unroll
    for (int i = 0; i < GB; ++i)
      gload16(bP[i] + k0, &Bs[buf][(tid + i * 256) * 8]);
  };

  const int fsl = (lg ^ (lr & 3)) << 3;   // swizzled 16B slot on read
  const int nt = K >> 5;
  STAGE(0, 0);
  asm volatile("s_waitcnt vmcnt(0)" ::: "memory");
  __builtin_amdgcn_s_barrier();

  for (int t = 0; t < nt; ++t) {
    if (t + 1 < nt) STAGE((t + 1) & 1, (t + 1) << 5);   // into the other buffer
    const u16* Ab = &As[t & 1][0];
    const u16* Bbuf = &Bs[t & 1][0];
    bf16x8 af[AM], bf[AN];
#pragma unroll
    for (int mi = 0; mi < AM; ++mi)
      af[mi] = *(const bf16x8*)&Ab[(wr * AM * 16 + mi * 16 + lr) * 32 + fsl];
#pragma unroll
    for (int ni = 0; ni < AN; ++ni)
      bf[ni] = *(const bf16x8*)&Bbuf[(wc * AN * 16 + ni * 16 + lr) * 32 + fsl];
#pragma unroll
    for (int mi = 0; mi < AM; ++mi)
#pragma unroll
      for (int ni = 0; ni < AN; ++ni)
        acc[mi][ni] = MFMA(af[mi], bf[ni], acc[mi][ni]);
    asm volatile("s_waitcnt vmcnt(0)" ::: "memory");
    __builtin_amdgcn_s_barrier();
  }

  // ---- epilogue
#pragma unroll
  for (int mi = 0; mi < AM; ++mi) {
#pragma unroll
    for (int ni = 0; ni < AN; ++ni) {
      const int gc = tn + wc * AN * 16 + ni * 16 + lr;
#pragma unroll
      for (int j = 0; j < 4; ++j) {
        const int gr = tm + wr * AM * 16 + mi * 16 + lg * 4 + j;
        float val = acc[mi][ni][j] + bias[gc];
        if constexpr (EPI == 0) {
          const int which = gc >> 10, hh = (gc >> 6) & 15, dd = gc & 63;
          const int bb2 = gr >> 10, ss2 = gr & 1023;
          const size_t dst = ((size_t)(bb2 * 16 + hh) * 1024 + ss2) * 64 + dd;
          if (which == 0)      q[dst] = f2bf(val * 0.125f);   // 1/sqrt(64)
          else if (which == 1) k[dst] = f2bf(val);
          else                 v[dst] = f2bf(val);
        } else if constexpr (EPI == 1) {
          const size_t idx = (size_t)gr * N + gc;
          outf[idx] = val + resid[idx];
        } else {
          outb[(size_t)gr * N + gc] = f2bf(gelu_tanh(val));
        }
      }
    }
  }
}

// ---------- flash attention v3 (no mask). Q pre-scaled. [B,H,S,D] bf16 -----
// 64 q-rows/block, 4 waves x 16 rows; KV tiles of 64.
// Q in regs (R8, verified). K cooperatively staged in LDS (R7, verified) —
// double-buffered with register prefetch (T14). V double-buffered with
// rotated transpose writes (R8, 0 conflicts). P through LDS. 2 syncs/iter.
__global__ __launch_bounds__(256) void attn3(const u16* __restrict__ qg,
                                             const u16* __restrict__ kg,
                                             const u16* __restrict__ vg,
                                             u16* __restrict__ ao) {
  __shared__ u16 Ks[2][64 * 64];   // [dbuf][kv][d] swizzled rows
  __shared__ u16 Vt[2][64 * 64];   // [dbuf][d][kv] swizzled
  __shared__ u16 Ps[64 * 64];      // [q][kv] swizzled
  const int tid = threadIdx.x;
  const int w = tid >> 6, ln = tid & 63;
  const int lr = ln & 15, lg = ln >> 4;
  const int bh = blockIdx.y;
  const int q0 = blockIdx.x * 64;
  const size_t head = (size_t)bh * (Ss * Dd);

  // Q fragments: row q0 + w*16 + lr, 16B contiguous per lane
  bf16x8 aq0, aq1;
  {
    const u16* qrow = qg + head + (size_t)(q0 + w * 16 + lr) * Dd;
    aq0 = *(const bf16x8*)(qrow + lg * 8);
    aq1 = *(const bf16x8*)(qrow + 32 + lg * 8);
  }

  // K staging geometry: chunk gi (0..511): row=gi>>3, col-slot g=gi&7;
  // thread covers gi=tid and gi=256+tid. Swizzled dest slot = g ^ (row&7).
  const int krow0 = tid >> 3, kg0 = tid & 7;          // gi = tid
  const int krow1 = (256 + tid) >> 3, kg1 = tid & 7;  // gi = 256+tid
  // V staging geometry (rotated-store; R8 verified)
  const int kv0 = tid >> 3;
  const int dsel = tid & 7, d0 = dsel * 8;

  auto KSTORE = [&](int buf, uint4 c0, uint4 c1) {
    *(uint4*)&Ks[buf][krow0 * 64 + ((kg0 ^ (krow0 & 7)) << 3)] = c0;
    *(uint4*)&Ks[buf][krow1 * 64 + ((kg1 ^ (krow1 & 7)) << 3)] = c1;
  };
  auto VSTORE = [&](int buf, uint4 dv, int kv) {
    const u16* pv = (const u16*)&dv;
#pragma unroll
    for (int jj = 0; jj < 8; ++jj) {
      const int j = (jj + dsel) & 7;
      const int dd = d0 + j;
      Vt[buf][dd * 64 + (kv & 7) + (((kv >> 3) ^ (dd & 7)) << 3)] = pv[j];
    }
  };

  { // prologue: stage K0, V0
    const u16* ksrc = kg + head;
    const u16* vsrc = vg + head;
    uint4 kc0 = *(const uint4*)(ksrc + krow0 * 64 + kg0 * 8);
    uint4 kc1 = *(const uint4*)(ksrc + krow1 * 64 + kg1 * 8);
    uint4 va  = *(const uint4*)(vsrc + (size_t)kv0 * Dd + d0);
    uint4 vb  = *(const uint4*)(vsrc + (size_t)(32 + kv0) * Dd + d0);
    KSTORE(0, kc0, kc1);
    VSTORE(0, va, kv0);
    VSTORE(0, vb, 32 + kv0);
  }
  __syncthreads();

  f32x4 zero4 = {0.f, 0.f, 0.f, 0.f};
  f32x4 acc_o[4] = {zero4, zero4, zero4, zero4};
  float mrow[4] = {-1e30f, -1e30f, -1e30f, -1e30f};
  float lrow[4] = {0.f, 0.f, 0.f, 0.f};

  for (int kt = 0; kt < 16; ++kt) {
    const int cur = kt & 1, nc = cur ^ 1;
    const bool more = (kt + 1) < 16;

    // T14: issue next-tile K/V loads early (land under QK^T+softmax+PV)
    uint4 nk0, nk1, nv0, nv1;
    if (more) {
      const u16* knxt = kg + head + (size_t)(kt + 1) * 64 * Dd;
      const u16* vnxt = vg + head + (size_t)(kt + 1) * 64 * Dd;
      nk0 = *(const uint4*)(knxt + krow0 * 64 + kg0 * 8);
      nk1 = *(const uint4*)(knxt + krow1 * 64 + kg1 * 8);
      nv0 = *(const uint4*)(vnxt + (size_t)kv0 * Dd + d0);
      nv1 = *(const uint4*)(vnxt + (size_t)(32 + kv0) * Dd + d0);
    }

    // QK^T from Ks[cur] (swizzled LDS reads, shared across waves)
    f32x4 sa[4];
#pragma unroll
    for (int kf = 0; kf < 4; ++kf) {
      bf16x8 bk0 = *(const bf16x8*)&Ks[cur][swz(kf * 16 + lr, lg * 8)];
      bf16x8 bk1 = *(const bf16x8*)&Ks[cur][swz(kf * 16 + lr, 32 + lg * 8)];
      f32x4 s = zero4;
      s = MFMA(aq0, bk0, s);
      s = MFMA(aq1, bk1, s);
      sa[kf] = s;
    }

    // online softmax (row = q, stats over kf frags + 16-lane kv group)
#pragma unroll
    for (int j = 0; j < 4; ++j) {
      float mx = fmaxf(fmaxf(sa[0][j], sa[1][j]), fmaxf(sa[2][j], sa[3][j]));
      mx = fmaxf(mx, __shfl_xor(mx, 1, 64));
      mx = fmaxf(mx, __shfl_xor(mx, 2, 64));
      mx = fmaxf(mx, __shfl_xor(mx, 4, 64));
      mx = fmaxf(mx, __shfl_xor(mx, 8, 64));
      const float nm = fmaxf(mrow[j], mx);
      const float corr = __expf(mrow[j] - nm);
      mrow[j] = nm;
      float ssum = 0.f;
#pragma unroll
      for (int kf = 0; kf < 4; ++kf) {
        const float p = __expf(sa[kf][j] - nm);
        sa[kf][j] = p;
        ssum += p;
      }
      ssum += __shfl_xor(ssum, 1, 64);
      ssum += __shfl_xor(ssum, 2, 64);
      ssum += __shfl_xor(ssum, 4, 64);
      ssum += __shfl_xor(ssum, 8, 64);
      lrow[j] = lrow[j] * corr + ssum;
#pragma unroll
      for (int df = 0; df < 4; ++df) acc_o[df][j] *= corr;
    }

    // P -> LDS (bf16, swizzled)
#pragma unroll
    for (int kf = 0; kf < 4; ++kf)
#pragma unroll
      for (int j = 0; j < 4; ++j)
        Ps[swz(w * 16 + lg * 4 + j, kf * 16 + lr)] = f2bf(sa[kf][j]);

    __syncthreads();   // SYNC1: P visible; Vt[cur] complete

    // PV: O[q 16][d 64] += P @ V  from Vt[cur]
    bf16x8 ap0 = *(const bf16x8*)&Ps[swz(w * 16 + lr, lg * 8)];
    bf16x8 ap1 = *(const bf16x8*)&Ps[swz(w * 16 + lr, 32 + lg * 8)];
#pragma unroll
    for (int df = 0; df < 4; ++df) {
      bf16x8 bv0 = *(const bf16x8*)&Vt[cur][swz(df * 16 + lr, lg * 8)];
      bf16x8 bv1 = *(const bf16x8*)&Vt[cur][swz(df * 16 + lr, 32 + lg * 8)];
      acc_o[df] = MFMA(ap0, bv0, acc_o[df]);
      acc_o[df] = MFMA(ap1, bv1, acc_o[df]);
    }

    // write prefetched K/V into the other buffers (readers after SYNC2)
    if (more) {
      KSTORE(nc, nk0, nk1);
      VSTORE(nc, nv0, kv0);
      VSTORE(nc, nv1, 32 + kv0);
    }
    __syncthreads();   // SYNC2: next buffers ready; Ps free for next iter
  }

  // epilogue: O/l -> attn_out [B,S,E] bf16
  const int b = bh >> 4, h = bh & 15;
#pragma unroll
  for (int df = 0; df < 4; ++df) {
#pragma unroll
    for (int j = 0; j < 4; ++j) {
      const int srow = q0 + w * 16 + lg * 4 + j;
      const int e = h * 64 + df * 16 + lr;
      ao[((size_t)b * Ss + srow) * Ee + e] = f2bf(acc_o[df][j] / lrow[j]);
    }
  }
}

// ---------- launcher ----------
extern "C" void kernel_launch(void* const* d_in, const int* in_sizes, int n_in,
                              void* d_out, int out_size, void* d_ws, size_t ws_size,
                              hipStream_t stream) {
  const float* x      = (const float*)d_in[0];
  const float* ln1_s  = (const float*)d_in[1];
  const float* ln1_b  = (const float*)d_in[2];
  const float* w_attn = (const float*)d_in[3];
  const float* b_attn = (const float*)d_in[4];
  const float* w_proj = (const float*)d_in[5];
  const float* b_proj = (const float*)d_in[6];
  const float* ln2_s  = (const float*)d_in[7];
  const float* ln2_b  = (const float*)d_in[8];
  const float* w_fc   = (const float*)d_in[9];
  const float* b_fc   = (const float*)d_in[10];
  const float* w_proj2= (const float*)d_in[11];
  const float* b_proj2= (const float*)d_in[12];
  float* out = (float*)d_out;

  char* base = (char*)d_ws;
  size_t off = 0;
  auto alloc = [&](size_t bytes) { char* p = base + off; off += bytes; return p; };
  u16* wA   = (u16*)alloc((size_t)3 * Ee * Ee * 2);  // 6 MB
  u16* wP   = (u16*)alloc((size_t)Ee * Ee * 2);      // 2 MB
  u16* wF   = (u16*)alloc((size_t)Ff * Ee * 2);      // 8 MB
  u16* wP2  = (u16*)alloc((size_t)Ee * Ff * 2);      // 8 MB
  u16* h1   = (u16*)alloc((size_t)Mm * Ee * 2);      // 8 MB (reused as h2)
  u16* qws  = (u16*)alloc((size_t)Mm * Ee * 2);      // 8 MB (q; mfc alias start)
  u16* kws  = (u16*)alloc((size_t)Mm * Ee * 2);      // 8 MB (k)
  u16* vws  = (u16*)alloc((size_t)Mm * Ee * 2);      // 8 MB (v)
  u16* aws  = (u16*)alloc((size_t)Mm * Ee * 2);      // 8 MB (attn out)
  float* x1 = (float*)alloc((size_t)Mm * Ee * 4);    // 16 MB
  u16* mfc  = qws;  // [4096,4096] bf16 aliases q/k/v/ao (all dead by then)

  // weights -> bf16 (every call; deterministic)
  cvt_bf16<<<3 * Ee * Ee / 2048, 256, 0, stream>>>(w_attn, wA, 3 * Ee * Ee);
  cvt_bf16<<<Ee * Ee / 2048, 256, 0, stream>>>(w_proj, wP, Ee * Ee);
  cvt_bf16<<<Ff * Ee / 2048, 256, 0, stream>>>(w_fc, wF, Ff * Ee);
  cvt_bf16<<<Ee * Ff / 2048, 256, 0, stream>>>(w_proj2, wP2, Ee * Ff);

  // LN1 -> h1
  ln_kernel<<<Mm, 256, 0, stream>>>(x, ln1_s, ln1_b, h1);
  // QKV GEMM: [4096,1024]@[1024,3072]^T -> q,k,v [B,H,S,D]  (128x64 tiles)
  gemm3<0, 4, 2><<<dim3(48, 32), 256, 0, stream>>>(h1, wA, b_attn, nullptr,
                                                   nullptr, nullptr, qws, kws, vws,
                                                   3 * Ee, Ee);
  // attention
  attn3<<<dim3(16, 64), 256, 0, stream>>>(qws, kws, vws, aws);
  // proj + residual -> x1 (fp32)  (64x64 tiles)
  gemm3<1, 2, 2><<<dim3(16, 64), 256, 0, stream>>>(aws, wP, b_proj, x,
                                                   x1, nullptr, nullptr, nullptr, nullptr,
                                                   Ee, Ee);
  // LN2 -> h1 (as h2)
  ln_kernel<<<Mm, 256, 0, stream>>>(x1, ln2_s, ln2_b, h1);
  // fc + gelu -> mfc (bf16)  (128x64 tiles)
  gemm3<2, 4, 2><<<dim3(64, 32), 256, 0, stream>>>(h1, wF, b_fc, nullptr,
                                                   nullptr, mfc, nullptr, nullptr, nullptr,
                                                   Ff, Ee);
  // proj2 + residual -> out (fp32)  (64x64 tiles)
  gemm3<1, 2, 2><<<dim3(16, 64), 256, 0, stream>>>(mfc, wP2, b_proj2, x1,
                                                   out, nullptr, nullptr, nullptr, nullptr,
                                                   Ee, Ff);
}

// Round 10
// 307.915 us; speedup vs baseline: 1.1127x; 1.0241x over previous
//
#include <hip/hip_runtime.h>

#define DEV __device__ __forceinline__

using bf16x8 = __attribute__((ext_vector_type(8))) __bf16;
using f32x4  = __attribute__((ext_vector_type(4))) float;
typedef unsigned int u32;
typedef unsigned short u16;
typedef unsigned long long u64;

static constexpr int Bb = 4, Ss = 1024, Ee = 1024, Hh = 16, Dd = 64, Ff = 4096;
static constexpr int Mm = Bb * Ss; // 4096 rows

// ---------- helpers ----------
DEV u16 f2bf(float f) {                 // fp32 -> bf16 RNE (finite inputs)
  union { float f; u32 u; } v; v.f = f;
  u32 r = v.u + 0x7fffu + ((v.u >> 16) & 1u);
  return (u16)(r >> 16);
}

DEV void gload16(const void* g, void* lds) {   // async global->LDS, 16B/lane
  __builtin_amdgcn_global_load_lds(
      (const __attribute__((address_space(1))) void*)(u64)g,
      (__attribute__((address_space(3))) void*)(u32)(u64)lds,
      16, 0, 0);
}

DEV float gelu_tanh(float x) {          // gelu_new (tanh approx)
  float x3 = x * x * x;
  float t  = tanhf(0.7978845608028654f * (x + 0.044715f * x3));
  return 0.5f * x * (1.0f + t);
}

// XOR-swizzle for [R][64] bf16 LDS tiles (attention): 16B-slot ^= row&7
DEV int swz(int row, int col) { return row * 64 + (col ^ ((row & 7) << 3)); }

DEV f32x4 MFMA(bf16x8 a, bf16x8 b, f32x4 c) {
  return __builtin_amdgcn_mfma_f32_16x16x32_bf16(a, b, c, 0, 0, 0);
}

// ---------- fp32 -> bf16 convert (8 elems/thread) ----------
__global__ __launch_bounds__(256) void cvt_bf16(const float* __restrict__ in,
                                                u16* __restrict__ out, int n) {
  int i = (blockIdx.x * 256 + threadIdx.x) * 8;
  if (i >= n) return;
  float4 a = *(const float4*)(in + i);
  float4 b = *(const float4*)(in + i + 4);
  uint4 o;
  o.x = (u32)f2bf(a.x) | ((u32)f2bf(a.y) << 16);
  o.y = (u32)f2bf(a.z) | ((u32)f2bf(a.w) << 16);
  o.z = (u32)f2bf(b.x) | ((u32)f2bf(b.y) << 16);
  o.w = (u32)f2bf(b.z) | ((u32)f2bf(b.w) << 16);
  *(uint4*)(out + i) = o;
}

// ---------- LayerNorm: one row (1024) per block, fp32 in -> bf16 out ----------
__global__ __launch_bounds__(256) void ln_kernel(const float* __restrict__ x,
                                                 const float* __restrict__ scale,
                                                 const float* __restrict__ bias,
                                                 u16* __restrict__ h) {
  const int row = blockIdx.x, tid = threadIdx.x;
  const float4 v = ((const float4*)(x + (size_t)row * Ee))[tid];
  float s  = v.x + v.y + v.z + v.w;
  float ss = v.x * v.x + v.y * v.y + v.z * v.z + v.w * v.w;
  for (int m = 1; m < 64; m <<= 1) {
    s  += __shfl_xor(s, m, 64);
    ss += __shfl_xor(ss, m, 64);
  }
  __shared__ float red[8];
  const int w = tid >> 6, ln = tid & 63;
  if (ln == 0) { red[w * 2] = s; red[w * 2 + 1] = ss; }
  __syncthreads();
  s  = red[0] + red[2] + red[4] + red[6];
  ss = red[1] + red[3] + red[5] + red[7];
  const float mu   = s * (1.0f / Ee);
  const float var  = ss * (1.0f / Ee) - mu * mu;
  const float rstd = rsqrtf(var + 1e-5f);
  const float4 sc = ((const float4*)scale)[tid];
  const float4 bi = ((const float4*)bias)[tid];
  ushort4 o;
  o.x = f2bf((v.x - mu) * rstd * sc.x + bi.x);
  o.y = f2bf((v.y - mu) * rstd * sc.y + bi.y);
  o.z = f2bf((v.z - mu) * rstd * sc.z + bi.z);
  o.w = f2bf((v.w - mu) * rstd * sc.w + bi.w);
  ((ushort4*)(h + (size_t)row * Ee))[tid] = o;
}

// ================= TLP-first GEMM (qkv/fc): C = A @ B^T (+epilogue) =========
// Tile BM x BN = (AM*32) x (AN*32); 4 waves in 2x2. BK=32; 2-deep ring; small
// LDS -> 6 blocks/CU. EPI: 0 = QKV split; 2 = gelu(+bias) -> bf16
template <int EPI, int AM, int AN>
__global__ __launch_bounds__(256, 6) void gemm3(
    const u16* __restrict__ A, const u16* __restrict__ Bw,
    const float* __restrict__ bias,
    u16* __restrict__ outb,
    u16* __restrict__ q, u16* __restrict__ k, u16* __restrict__ v,
    int N, int K) {
  constexpr int BM = AM * 32, BN = AN * 32;
  constexpr int GA = BM / 64, GB = BN / 64;
  __shared__ u16 As[2][BM * 32];
  __shared__ u16 Bs[2][BN * 32];
  const int tid = threadIdx.x;
  const int w = tid >> 6, ln = tid & 63;
  const int lr = ln & 15, lg = ln >> 4;
  const int wr = w >> 1, wc = w & 1;

  const int nwg = gridDim.x * gridDim.y;
  const int bid = blockIdx.y * gridDim.x + blockIdx.x;
  const int sid = (bid & 7) * (nwg >> 3) + (bid >> 3);
  const int bx = sid % gridDim.x, by = sid / gridDim.x;
  const int tm = by * BM, tn = bx * BN;

  f32x4 acc[AM][AN];
  f32x4 zero4 = {0.f, 0.f, 0.f, 0.f};
#pragma unroll
  for (int i = 0; i < AM; ++i)
#pragma unroll
    for (int j = 0; j < AN; ++j) acc[i][j] = zero4;

  const int r0 = tid >> 2;
  const int cs = ((tid & 3) ^ (r0 & 3)) * 8;    // pre-swizzled source slot
  const u16* aP[GA];
  const u16* bP[GB];
#pragma unroll
  for (int i = 0; i < GA; ++i) aP[i] = A + (size_t)(tm + r0 + i * 64) * K + cs;
#pragma unroll
  for (int i = 0; i < GB; ++i) bP[i] = Bw + (size_t)(tn + r0 + i * 64) * K + cs;

  auto STAGE = [&](int buf, int k0) {
#pragma unroll
    for (int i = 0; i < GA; ++i)
      gload16(aP[i] + k0, &As[buf][(tid + i * 256) * 8]);
#pragma unroll
    for (int i = 0; i < GB; ++i)
      gload16(bP[i] + k0, &Bs[buf][(tid + i * 256) * 8]);
  };

  const int fsl = (lg ^ (lr & 3)) << 3;
  const int nt = K >> 5;
  STAGE(0, 0);
  asm volatile("s_waitcnt vmcnt(0)" ::: "memory");
  __builtin_amdgcn_s_barrier();

  for (int t = 0; t < nt; ++t) {
    if (t + 1 < nt) STAGE((t + 1) & 1, (t + 1) << 5);
    const u16* Ab = &As[t & 1][0];
    const u16* Bbuf = &Bs[t & 1][0];
    bf16x8 af[AM], bf[AN];
#pragma unroll
    for (int mi = 0; mi < AM; ++mi)
      af[mi] = *(const bf16x8*)&Ab[(wr * AM * 16 + mi * 16 + lr) * 32 + fsl];
#pragma unroll
    for (int ni = 0; ni < AN; ++ni)
      bf[ni] = *(const bf16x8*)&Bbuf[(wc * AN * 16 + ni * 16 + lr) * 32 + fsl];
#pragma unroll
    for (int mi = 0; mi < AM; ++mi)
#pragma unroll
      for (int ni = 0; ni < AN; ++ni)
        acc[mi][ni] = MFMA(af[mi], bf[ni], acc[mi][ni]);
    asm volatile("s_waitcnt vmcnt(0)" ::: "memory");
    __builtin_amdgcn_s_barrier();
  }

#pragma unroll
  for (int mi = 0; mi < AM; ++mi) {
#pragma unroll
    for (int ni = 0; ni < AN; ++ni) {
      const int gc = tn + wc * AN * 16 + ni * 16 + lr;
#pragma unroll
      for (int j = 0; j < 4; ++j) {
        const int gr = tm + wr * AM * 16 + mi * 16 + lg * 4 + j;
        float val = acc[mi][ni][j] + bias[gc];
        if constexpr (EPI == 0) {
          const int which = gc >> 10, hh = (gc >> 6) & 15, dd = gc & 63;
          const int bb2 = gr >> 10, ss2 = gr & 1023;
          const size_t dst = ((size_t)(bb2 * 16 + hh) * 1024 + ss2) * 64 + dd;
          if (which == 0)      q[dst] = f2bf(val * 0.125f);   // 1/sqrt(64)
          else if (which == 1) k[dst] = f2bf(val);
          else                 v[dst] = f2bf(val);
        } else {
          outb[(size_t)gr * N + gc] = f2bf(gelu_tanh(val));
        }
      }
    }
  }
}

// ---------- bf16 GEMM v2 (128x128, proj/proj2): C = A @ B^T + bias + resid --
__global__ __launch_bounds__(256, 3) void gemm2r(
    const u16* __restrict__ A, const u16* __restrict__ Bw,
    const float* __restrict__ bias, const float* __restrict__ resid,
    float* __restrict__ outf, int N, int K) {
  __shared__ u16 As[3][128 * 32];
  __shared__ u16 Bs[3][128 * 32];
  const int tid = threadIdx.x;
  const int w = tid >> 6, ln = tid & 63;
  const int lr = ln & 15, lg = ln >> 4;

  const int nwg = gridDim.x * gridDim.y;
  const int bid = blockIdx.y * gridDim.x + blockIdx.x;
  const int sid = (bid & 7) * (nwg >> 3) + (bid >> 3);
  const int bx = sid % gridDim.x, by = sid / gridDim.x;
  const int tm = by * 128, tn = bx * 128;
  const int wr = (w >> 1) * 64, wc = (w & 1) * 64;

  f32x4 zero4 = {0.f, 0.f, 0.f, 0.f};
  f32x4 acc[4][4];
#pragma unroll
  for (int i = 0; i < 4; ++i)
#pragma unroll
    for (int j = 0; j < 4; ++j) acc[i][j] = zero4;

  const int r0 = tid >> 2, sl = tid & 3;
  const int cs = (sl ^ (r0 & 3)) * 8;
  const u16* aP0 = A  + (size_t)(tm + r0) * K + cs;
  const u16* aP1 = A  + (size_t)(tm + 64 + r0) * K + cs;
  const u16* bP0 = Bw + (size_t)(tn + r0) * K + cs;
  const u16* bP1 = Bw + (size_t)(tn + 64 + r0) * K + cs;

  auto STAGE = [&](int buf, int k0) {
    gload16(aP0 + k0, &As[buf][tid * 8]);
    gload16(aP1 + k0, &As[buf][(256 + tid) * 8]);
    gload16(bP0 + k0, &Bs[buf][tid * 8]);
    gload16(bP1 + k0, &Bs[buf][(256 + tid) * 8]);
  };

  const int nt = K >> 5;
  STAGE(0, 0);
  STAGE(1, 32);
  asm volatile("s_waitcnt vmcnt(4)" ::: "memory");
  __builtin_amdgcn_s_barrier();
  __builtin_amdgcn_sched_barrier(0);

  for (int t = 0; t < nt; ++t) {
    const int cur = t % 3;
    const bool more = (t + 2) < nt;
    if (more) STAGE((t + 2) % 3, (t + 2) << 5);

    bf16x8 af[4], bb[4];
#pragma unroll
    for (int mi = 0; mi < 4; ++mi) {
      const int row = wr + mi * 16 + lr;
      af[mi] = *(const bf16x8*)&As[cur][row * 32 + ((lg ^ (row & 3)) << 3)];
    }
#pragma unroll
    for (int ni = 0; ni < 4; ++ni) {
      const int row = wc + ni * 16 + lr;
      bb[ni] = *(const bf16x8*)&Bs[cur][row * 32 + ((lg ^ (row & 3)) << 3)];
    }
    __builtin_amdgcn_s_setprio(1);
#pragma unroll
    for (int mi = 0; mi < 4; ++mi)
#pragma unroll
      for (int ni = 0; ni < 4; ++ni)
        acc[mi][ni] = MFMA(af[mi], bb[ni], acc[mi][ni]);
    __builtin_amdgcn_s_setprio(0);
    __builtin_amdgcn_sched_barrier(0);
    if (more) asm volatile("s_waitcnt vmcnt(4)" ::: "memory");
    else      asm volatile("s_waitcnt vmcnt(0)" ::: "memory");
    __builtin_amdgcn_s_barrier();
    __builtin_amdgcn_sched_barrier(0);
  }

#pragma unroll
  for (int mi = 0; mi < 4; ++mi) {
#pragma unroll
    for (int ni = 0; ni < 4; ++ni) {
      const int gc = tn + wc + ni * 16 + lr;
#pragma unroll
      for (int j = 0; j < 4; ++j) {
        const int gr = tm + wr + mi * 16 + lg * 4 + j;
        const size_t idx = (size_t)gr * N + gc;
        outf[idx] = acc[mi][ni][j] + bias[gc] + resid[idx];
      }
    }
  }
}

// ---------- flash attention v4 (no mask). Q pre-scaled. [B,H,S,D] bf16 -----
// = R7's measured-best structure (Qs/Ks/Vt/Ps staged, 3 syncs) with:
//  (a) XCD head-grouping block remap: all 16 q-tiles of a head on ONE XCD
//      (same bid mod 8) -> per-XCD L2 fetches each head's K/V once.
//  (b) rotated V-transpose writes (R8-proven: 14.7M bank conflicts -> 0).
__global__ __launch_bounds__(256) void attn4(const u16* __restrict__ qg,
                                             const u16* __restrict__ kg,
                                             const u16* __restrict__ vg,
                                             u16* __restrict__ ao) {
  __shared__ u16 Qs[64 * 64], Ks[64 * 64], Vt[64 * 64], Ps[64 * 64];
  const int tid = threadIdx.x;
  const int w = tid >> 6, ln = tid & 63;
  const int lr = ln & 15, lg = ln >> 4;

  // head-grouping remap: bid = xcd + 8*sub + 64*qtile (bijective on [0,1024))
  const int bid = blockIdx.x;
  const int bh = (bid & 7) * 8 + ((bid >> 3) & 7);   // head id (b*16+h)
  const int q0 = (bid >> 6) * 64;
  const size_t head = (size_t)bh * (Ss * Dd);

  const int dsel = tid & 7, d0 = dsel * 8;

  { // stage Q (swizzled)
    const u16* src = qg + head + (size_t)q0 * Dd;
#pragma unroll
    for (int i = 0; i < 2; ++i) {
      const int gi = i * 256 + tid, row = gi >> 3, g = gi & 7;
      *(uint4*)&Qs[row * 64 + ((g ^ (row & 7)) << 3)] = *(const uint4*)(src + gi * 8);
    }
  }

  f32x4 zero4 = {0.f, 0.f, 0.f, 0.f};
  f32x4 acc_o[4] = {zero4, zero4, zero4, zero4};
  float mrow[4] = {-1e30f, -1e30f, -1e30f, -1e30f};
  float lrow[4] = {0.f, 0.f, 0.f, 0.f};

  for (int kt = 0; kt < 16; ++kt) {
    __syncthreads();  // prev-tile Ks/Vt reads complete before restage
    const u16* ksrc = kg + head + (size_t)kt * 64 * Dd;
    const u16* vsrc = vg + head + (size_t)kt * 64 * Dd;
#pragma unroll
    for (int i = 0; i < 2; ++i) {
      const int gi = i * 256 + tid, row = gi >> 3, g = gi & 7;
      *(uint4*)&Ks[row * 64 + ((g ^ (row & 7)) << 3)] = *(const uint4*)(ksrc + gi * 8);
    }
#pragma unroll
    for (int i = 0; i < 2; ++i) {  // V transposed (rotated write order)
      const int kv = i * 32 + (tid >> 3);
      uint4 dv = *(const uint4*)(vsrc + (size_t)kv * Dd + d0);
      const u16* pv = (const u16*)&dv;
#pragma unroll
      for (int jj = 0; jj < 8; ++jj) {
        const int j = (jj + dsel) & 7;
        const int dd = d0 + j;
        Vt[dd * 64 + (kv & 7) + (((kv >> 3) ^ (dd & 7)) << 3)] = pv[j];
      }
    }
    __syncthreads();

    // QK^T: S[q 16][kv 64] per wave
    bf16x8 aq[2];
#pragma unroll
    for (int kk = 0; kk < 2; ++kk)
      aq[kk] = *(const bf16x8*)&Qs[swz(w * 16 + lr, kk * 32 + lg * 8)];
    f32x4 sa[4];
#pragma unroll
    for (int kf = 0; kf < 4; ++kf) {
      f32x4 s = zero4;
#pragma unroll
      for (int kk = 0; kk < 2; ++kk) {
        bf16x8 bk = *(const bf16x8*)&Ks[swz(kf * 16 + lr, kk * 32 + lg * 8)];
        s = MFMA(aq[kk], bk, s);
      }
      sa[kf] = s;
    }

    // online softmax
#pragma unroll
    for (int j = 0; j < 4; ++j) {
      float mx = fmaxf(fmaxf(sa[0][j], sa[1][j]), fmaxf(sa[2][j], sa[3][j]));
      mx = fmaxf(mx, __shfl_xor(mx, 1, 64));
      mx = fmaxf(mx, __shfl_xor(mx, 2, 64));
      mx = fmaxf(mx, __shfl_xor(mx, 4, 64));
      mx = fmaxf(mx, __shfl_xor(mx, 8, 64));
      const float nm = fmaxf(mrow[j], mx);
      const float corr = __expf(mrow[j] - nm);
      mrow[j] = nm;
      float ssum = 0.f;
#pragma unroll
      for (int kf = 0; kf < 4; ++kf) {
        const float p = __expf(sa[kf][j] - nm);
        sa[kf][j] = p;
        ssum += p;
      }
      ssum += __shfl_xor(ssum, 1, 64);
      ssum += __shfl_xor(ssum, 2, 64);
      ssum += __shfl_xor(ssum, 4, 64);
      ssum += __shfl_xor(ssum, 8, 64);
      lrow[j] = lrow[j] * corr + ssum;
#pragma unroll
      for (int df = 0; df < 4; ++df) acc_o[df][j] *= corr;
    }

    // P -> LDS (bf16, swizzled)
#pragma unroll
    for (int kf = 0; kf < 4; ++kf)
#pragma unroll
      for (int j = 0; j < 4; ++j)
        Ps[swz(w * 16 + lg * 4 + j, kf * 16 + lr)] = f2bf(sa[kf][j]);

    __syncthreads();

    // PV: O[q 16][d 64] += P @ V
    bf16x8 ap[2];
#pragma unroll
    for (int kk = 0; kk < 2; ++kk)
      ap[kk] = *(const bf16x8*)&Ps[swz(w * 16 + lr, kk * 32 + lg * 8)];
#pragma unroll
    for (int df = 0; df < 4; ++df) {
#pragma unroll
      for (int kk = 0; kk < 2; ++kk) {
        bf16x8 bv = *(const bf16x8*)&Vt[swz(df * 16 + lr, kk * 32 + lg * 8)];
        acc_o[df] = MFMA(ap[kk], bv, acc_o[df]);
      }
    }
  }

  // epilogue: O/l -> attn_out [B,S,E] bf16
  const int b = bh >> 4, h = bh & 15;
#pragma unroll
  for (int df = 0; df < 4; ++df) {
#pragma unroll
    for (int j = 0; j < 4; ++j) {
      const int srow = q0 + w * 16 + lg * 4 + j;
      const int e = h * 64 + df * 16 + lr;
      ao[((size_t)b * Ss + srow) * Ee + e] = f2bf(acc_o[df][j] / lrow[j]);
    }
  }
}

// ---------- launcher ----------
extern "C" void kernel_launch(void* const* d_in, const int* in_sizes, int n_in,
                              void* d_out, int out_size, void* d_ws, size_t ws_size,
                              hipStream_t stream) {
  const float* x      = (const float*)d_in[0];
  const float* ln1_s  = (const float*)d_in[1];
  const float* ln1_b  = (const float*)d_in[2];
  const float* w_attn = (const float*)d_in[3];
  const float* b_attn = (const float*)d_in[4];
  const float* w_proj = (const float*)d_in[5];
  const float* b_proj = (const float*)d_in[6];
  const float* ln2_s  = (const float*)d_in[7];
  const float* ln2_b  = (const float*)d_in[8];
  const float* w_fc   = (const float*)d_in[9];
  const float* b_fc   = (const float*)d_in[10];
  const float* w_proj2= (const float*)d_in[11];
  const float* b_proj2= (const float*)d_in[12];
  float* out = (float*)d_out;

  char* base = (char*)d_ws;
  size_t off = 0;
  auto alloc = [&](size_t bytes) { char* p = base + off; off += bytes; return p; };
  u16* wA   = (u16*)alloc((size_t)3 * Ee * Ee * 2);  // 6 MB
  u16* wP   = (u16*)alloc((size_t)Ee * Ee * 2);      // 2 MB
  u16* wF   = (u16*)alloc((size_t)Ff * Ee * 2);      // 8 MB
  u16* wP2  = (u16*)alloc((size_t)Ee * Ff * 2);      // 8 MB
  u16* h1   = (u16*)alloc((size_t)Mm * Ee * 2);      // 8 MB (reused as h2)
  u16* qws  = (u16*)alloc((size_t)Mm * Ee * 2);      // 8 MB (q; mfc alias start)
  u16* kws  = (u16*)alloc((size_t)Mm * Ee * 2);      // 8 MB (k)
  u16* vws  = (u16*)alloc((size_t)Mm * Ee * 2);      // 8 MB (v)
  u16* aws  = (u16*)alloc((size_t)Mm * Ee * 2);      // 8 MB (attn out)
  float* x1 = (float*)alloc((size_t)Mm * Ee * 4);    // 16 MB
  u16* mfc  = qws;  // [4096,4096] bf16 aliases q/k/v/ao (all dead by then)

  // weights -> bf16 (every call; deterministic)
  cvt_bf16<<<3 * Ee * Ee / 2048, 256, 0, stream>>>(w_attn, wA, 3 * Ee * Ee);
  cvt_bf16<<<Ee * Ee / 2048, 256, 0, stream>>>(w_proj, wP, Ee * Ee);
  cvt_bf16<<<Ff * Ee / 2048, 256, 0, stream>>>(w_fc, wF, Ff * Ee);
  cvt_bf16<<<Ee * Ff / 2048, 256, 0, stream>>>(w_proj2, wP2, Ee * Ff);

  // LN1 -> h1
  ln_kernel<<<Mm, 256, 0, stream>>>(x, ln1_s, ln1_b, h1);
  // QKV GEMM: [4096,1024]@[1024,3072]^T -> q,k,v [B,H,S,D]  (128x64 tiles)
  gemm3<0, 4, 2><<<dim3(48, 32), 256, 0, stream>>>(h1, wA, b_attn,
                                                   nullptr, qws, kws, vws,
                                                   3 * Ee, Ee);
  // attention (XCD head-grouped 1D grid)
  attn4<<<1024, 256, 0, stream>>>(qws, kws, vws, aws);
  // proj + residual -> x1 (fp32)  (128x128, 3-ring)
  gemm2r<<<dim3(8, 32), 256, 0, stream>>>(aws, wP, b_proj, x, x1, Ee, Ee);
  // LN2 -> h1 (as h2)
  ln_kernel<<<Mm, 256, 0, stream>>>(x1, ln2_s, ln2_b, h1);
  // fc + gelu -> mfc (bf16)  (128x64 tiles)
  gemm3<2, 4, 2><<<dim3(64, 32), 256, 0, stream>>>(h1, wF, b_fc,
                                                   mfc, nullptr, nullptr, nullptr,
                                                   Ff, Ee);
  // proj2 + residual -> out (fp32)  (128x128, 3-ring)
  gemm2r<<<dim3(8, 32), 256, 0, stream>>>(mfc, wP2, b_proj2, x1, out, Ee, Ff);
}